// Round 7
// baseline (279.762 us; speedup 1.0000x reference)
//
#include <hip/hip_runtime.h>

#define N_USER 100000
#define N_ITEM 100000
#define NEDGE  500000
#define DEGCAP 32

// phase-1 striped grid sections
#define B_FILL 3908   // 2 x 1954 edge blocks
#define B_GEMM 3126   // 2 x 1563 self-GEMM blocks
#define B_CONV 12500  // 2 x 6250 conversion blocks
#define B_WT   384
#define B_TOT  (B_FILL + B_GEMM + B_CONV + B_WT)  // 19918

typedef __attribute__((ext_vector_type(8))) short short8;
typedef __attribute__((ext_vector_type(4))) float f32x4;

__device__ __forceinline__ unsigned short f2bf(float f) {
  union { float f; unsigned int u; } x{f};
  unsigned int r = x.u + 0x7fffu + ((x.u >> 16) & 1u);  // RTN-even
  return (unsigned short)(r >> 16);
}
__device__ __forceinline__ float bf2f(unsigned short u) {
  union { unsigned int u; float f; } x{(unsigned int)u << 16};
  return x.f;
}

// ---------------------------------------------------------------------------
// phase1_k, striped so latency-bound / BW-bound / MFMA blocks co-run:
//   b%5==0 (first 3908): padded-CSR fill (atomic cursor + nt scatter store)
//   b%5==1 (first 3126): self-GEMM h0 = emb@W1_0 + b1_0 -> bf16 into d_out
//                        (W in VGPRs from L2-hot table; A staged in 16KB LDS)
//   rest              : emb fp32->bf16 conversion, then WT weight prep
// All sections independent; __syncthreads only on the (block-uniform) gemm
// path. 16KB LDS / ~128 VGPR so streaming blocks keep decent occupancy.
// ---------------------------------------------------------------------------
__global__ __launch_bounds__(256, 4) void phase1_k(
    const int* __restrict__ src_ui, const int* __restrict__ dst_ui,
    int* __restrict__ cur_i, int* __restrict__ csr_ui,
    const int* __restrict__ src_iu, const int* __restrict__ dst_iu,
    int* __restrict__ cur_u, int* __restrict__ csr_iu,
    const float* __restrict__ emb_u, const float* __restrict__ emb_i,
    unsigned short* __restrict__ ebu, unsigned short* __restrict__ ebi,
    const float* __restrict__ W10, const float* __restrict__ W1ui,
    const float* __restrict__ W1iu, const float* __restrict__ W20,
    const float* __restrict__ W2ui, const float* __restrict__ W2iu,
    unsigned short* __restrict__ WT1i, unsigned short* __restrict__ WT1u,
    unsigned short* __restrict__ WT2i, unsigned short* __restrict__ WT2u,
    const float* __restrict__ b10,
    unsigned short* __restrict__ h0u, unsigned short* __restrict__ h0i) {
  __shared__ short As[64 * 128];  // 16 KB (self-GEMM A tile)
  int b = blockIdx.x, tid = threadIdx.x;
  int q = b / 5, m = b % 5;

  if (m == 0 && q < B_FILL) {
    // ---- padded-CSR fill ----
    const int *src, *dst; int *cur, *csr;
    int bb = q;
    if (bb < 1954) { src = src_ui; dst = dst_ui; cur = cur_i; csr = csr_ui; }
    else { bb -= 1954; src = src_iu; dst = dst_iu; cur = cur_u; csr = csr_iu; }
    int e = bb * 256 + tid;
    if (e < NEDGE) {
      int d = dst[e];
      int p = atomicAdd(&cur[d], 1);
      if (p < DEGCAP) __builtin_nontemporal_store(src[e], &csr[d * DEGCAP + p]);
    }
  } else if (m == 1 && q < B_GEMM) {
    // ---- self-GEMM: h0 = emb @ W1_0 + b1_0 (bf16 out) ----
    const float* A; unsigned short* h0; int blk;
    if (q < 1563) { A = emb_i; h0 = h0i; blk = q; }
    else { A = emb_u; h0 = h0u; blk = q - 1563; }
    int row0 = blk * 64;
    int lane = tid & 63, wave = tid >> 6;
    // preload this wave's W slice into VGPRs (64KB table, L2-hot)
    short8 wf[2][4];
#pragma unroll
    for (int cf = 0; cf < 2; ++cf) {
      int n = wave * 32 + cf * 16 + (lane & 15);
#pragma unroll
      for (int ks = 0; ks < 4; ++ks) {
        int k0 = ks * 32 + (lane >> 4) * 8;
#pragma unroll
        for (int j = 0; j < 8; ++j)
          wf[cf][ks][j] = (short)f2bf(W10[(k0 + j) * 128 + n]);
      }
    }
    // stage A tile (fp32 -> bf16, swizzled)
#pragma unroll
    for (int it = 0; it < 4; ++it) {
      int chunk = tid + it * 256;
      int row = chunk >> 4, c16 = chunk & 15;
      int gr = row0 + row; if (gr > N_USER - 1) gr = N_USER - 1;
      const float* s = A + (size_t)gr * 128 + c16 * 8;
      float4 x = *(const float4*)s;
      float4 y = *(const float4*)(s + 4);
      short8 v{(short)f2bf(x.x), (short)f2bf(x.y), (short)f2bf(x.z), (short)f2bf(x.w),
               (short)f2bf(y.x), (short)f2bf(y.y), (short)f2bf(y.z), (short)f2bf(y.w)};
      int byteoff = row * 256 + ((c16 * 16) ^ ((row & 7) << 4));
      *(short8*)((char*)As + byteoff) = v;
    }
    __syncthreads();
    f32x4 acc[4][2] = {};
#pragma unroll
    for (int ks = 0; ks < 4; ++ks) {
      short8 af[4];
#pragma unroll
      for (int rf = 0; rf < 4; ++rf) {
        int row = rf * 16 + (lane & 15);
        int c16 = ks * 4 + (lane >> 4);
        int byteoff = row * 256 + ((c16 * 16) ^ ((row & 7) << 4));
        af[rf] = *(const short8*)((const char*)As + byteoff);
      }
#pragma unroll
      for (int rf = 0; rf < 4; ++rf)
#pragma unroll
        for (int cf = 0; cf < 2; ++cf)
          acc[rf][cf] = __builtin_amdgcn_mfma_f32_16x16x32_bf16(
              af[rf], wf[cf][ks], acc[rf][cf], 0, 0, 0);
    }
#pragma unroll
    for (int cf = 0; cf < 2; ++cf) {
      int c = wave * 32 + cf * 16 + (lane & 15);
      float bb0 = b10[c];
#pragma unroll
      for (int rf = 0; rf < 4; ++rf)
#pragma unroll
        for (int j = 0; j < 4; ++j) {
          int r = row0 + rf * 16 + (lane >> 4) * 4 + j;
          if (r < N_USER)
            h0[(size_t)r * 128 + c] = f2bf(acc[rf][cf][j] + bb0);
        }
    }
  } else {
    int fills_before = min((b + 4) / 5, B_FILL);
    int gems_before  = min((b + 3) / 5, B_GEMM);
    int sr = b - fills_before - gems_before;  // [0, 12884)
    if (sr < B_CONV) {
      // ---- emb fp32 -> bf16 ----
      int blk = sr;
      const float* src; unsigned short* dstp;
      if (blk < 6250) { src = emb_u; dstp = ebu; }
      else { blk -= 6250; src = emb_i; dstp = ebi; }
      size_t base = (size_t)blk * 2048 + (size_t)tid * 8;
      float4 x = *(const float4*)(src + base);
      float4 y = *(const float4*)(src + base + 4);
      short8 v{(short)f2bf(x.x), (short)f2bf(x.y), (short)f2bf(x.z), (short)f2bf(x.w),
               (short)f2bf(y.x), (short)f2bf(y.y), (short)f2bf(y.z), (short)f2bf(y.w)};
      *(short8*)(dstp + base) = v;
    } else {
      // ---- transposed bf16 weight prep: WT[N][256] ----
      int t = (sr - B_CONV) * 256 + tid;  // 0..98303
      if (t < 32768) {
        int n = t >> 8, k = t & 255;
        float v = (k < 128) ? W10[k * 128 + n] : W1ui[(k - 128) * 128 + n];
        WT1i[t] = f2bf(v);
      } else if (t < 65536) {
        int u = t - 32768; int n = u >> 8, k = u & 255;
        float v = (k < 128) ? W10[k * 128 + n] : W1iu[(k - 128) * 128 + n];
        WT1u[u] = f2bf(v);
      } else if (t < 81920) {
        int u = t - 65536; int n = u >> 8, k = u & 255;
        float v = (k < 128) ? W20[k * 64 + n] : W2ui[(k - 128) * 64 + n];
        WT2i[u] = f2bf(v);
      } else {
        int u = t - 81920; int n = u >> 8, k = u & 255;
        float v = (k < 128) ? W20[k * 64 + n] : W2iu[(k - 128) * 64 + n];
        WT2u[u] = f2bf(v);
      }
    }
  }
}

// ---------------------------------------------------------------------------
// Gather-mean aggregation (bf16 src, 128-dim), both directions per dispatch.
// Padded CSR. 16 lanes/node (short8/lane), 16 nodes/block, x4 unroll with
// index prefetch. No LDS, high occupancy (R5 lesson: keep latency-bound
// gather out of LDS-capped kernels).
// ---------------------------------------------------------------------------
__global__ __launch_bounds__(256) void agg2_k(
    const unsigned short* __restrict__ featA, const int* __restrict__ curA,
    const int* __restrict__ csrA, unsigned short* __restrict__ outA,
    const unsigned short* __restrict__ featB, const int* __restrict__ curB,
    const int* __restrict__ csrB, unsigned short* __restrict__ outB,
    int nbA) {
  int b = blockIdx.x;
  const unsigned short* feat; const int* cur; const int* csr; unsigned short* out;
  if (b < nbA) { feat = featA; cur = curA; csr = csrA; out = outA; }
  else { b -= nbA; feat = featB; cur = curB; csr = csrB; out = outB; }
  int node = b * 16 + (threadIdx.x >> 4);
  int ln = threadIdx.x & 15;
  int deg = min(cur[node], DEGCAP);
  const int* cp = csr + (size_t)node * DEGCAP;
  float a[8] = {0, 0, 0, 0, 0, 0, 0, 0};
  int j = 0;
  if (j + 4 <= deg) {
    int i0 = cp[0], i1 = cp[1], i2 = cp[2], i3 = cp[3];
    for (;;) {
      bool more = (j + 8 <= deg);
      int n0, n1, n2, n3;
      if (more) { n0 = cp[j + 4]; n1 = cp[j + 5]; n2 = cp[j + 6]; n3 = cp[j + 7]; }
      short8 v0 = *(const short8*)(feat + (size_t)i0 * 128 + ln * 8);
      short8 v1 = *(const short8*)(feat + (size_t)i1 * 128 + ln * 8);
      short8 v2 = *(const short8*)(feat + (size_t)i2 * 128 + ln * 8);
      short8 v3 = *(const short8*)(feat + (size_t)i3 * 128 + ln * 8);
#pragma unroll
      for (int d = 0; d < 8; ++d)
        a[d] += (bf2f((unsigned short)v0[d]) + bf2f((unsigned short)v1[d])) +
                (bf2f((unsigned short)v2[d]) + bf2f((unsigned short)v3[d]));
      j += 4;
      if (!more) break;
      i0 = n0; i1 = n1; i2 = n2; i3 = n3;
    }
  }
  if (j + 2 <= deg) {
    int i0 = cp[j], i1 = cp[j + 1];
    short8 v0 = *(const short8*)(feat + (size_t)i0 * 128 + ln * 8);
    short8 v1 = *(const short8*)(feat + (size_t)i1 * 128 + ln * 8);
#pragma unroll
    for (int d = 0; d < 8; ++d)
      a[d] += bf2f((unsigned short)v0[d]) + bf2f((unsigned short)v1[d]);
    j += 2;
  }
  if (j < deg) {
    short8 v = *(const short8*)(feat + (size_t)cp[j] * 128 + ln * 8);
#pragma unroll
    for (int d = 0; d < 8; ++d) a[d] += bf2f((unsigned short)v[d]);
  }
  float sc = deg ? 1.f / (float)deg : 0.f;
  short8 pk;
#pragma unroll
  for (int d = 0; d < 8; ++d) pk[d] = (short)f2bf(a[d] * sc);
  *(short8*)(out + (size_t)node * 128 + ln * 8) = pk;
}

// ---------------------------------------------------------------------------
// Layer-1 edge-GEMM + finalize, both ntypes per dispatch:
//   h = lrelu(h0 + agg@We^T + (deg>0)*be)      K=128 only (self half is h0).
// A2: agg bf16. WT: [N][256], second half = We^T. h0: bf16 (d_out scratch).
// ---------------------------------------------------------------------------
__global__ __launch_bounds__(256) void egemm_k(
    const unsigned short* __restrict__ A2a, const unsigned short* __restrict__ h0a,
    const unsigned short* __restrict__ WTa, const float* __restrict__ bea,
    const int* __restrict__ cura, unsigned short* __restrict__ outa,
    const unsigned short* __restrict__ A2b, const unsigned short* __restrict__ h0b,
    const unsigned short* __restrict__ WTb, const float* __restrict__ beb,
    const int* __restrict__ curb, unsigned short* __restrict__ outb,
    int nbA) {
  __shared__ short As[64 * 128];
  __shared__ short Ws[128 * 128];
  __shared__ float degmask[64];

  int blk = blockIdx.x;
  const unsigned short *A2, *h0, *WT; const float* be; const int* cur;
  unsigned short* outp;
  if (blk < nbA) { A2 = A2a; h0 = h0a; WT = WTa; be = bea; cur = cura; outp = outa; }
  else { blk -= nbA; A2 = A2b; h0 = h0b; WT = WTb; be = beb; cur = curb; outp = outb; }

  const int tid = threadIdx.x;
  const int lane = tid & 63;
  const int wave = tid >> 6;
  const int row0 = blk * 64;
  const int colbase = wave * 32;

  if (tid < 64) {
    int r = row0 + tid;
    degmask[tid] = (r < N_USER && cur[r] > 0) ? 1.f : 0.f;
  }
#pragma unroll
  for (int it = 0; it < 4; ++it) {
    int chunk = tid + it * 256;
    int row = chunk >> 4, c16 = chunk & 15;
    int gr = row0 + row; if (gr > N_USER - 1) gr = N_USER - 1;
    short8 v = *(const short8*)(A2 + (size_t)gr * 128 + c16 * 8);
    int byteoff = row * 256 + ((c16 * 16) ^ ((row & 7) << 4));
    *(short8*)((char*)As + byteoff) = v;
  }
#pragma unroll
  for (int it = 0; it < 8; ++it) {
    int chunk = tid + it * 256;
    int n = chunk >> 4, c16 = chunk & 15;
    short8 v = *(const short8*)(WT + (size_t)n * 256 + 128 + c16 * 8);
    int byteoff = n * 256 + ((c16 * 16) ^ ((n & 7) << 4));
    *(short8*)((char*)Ws + byteoff) = v;
  }
  __syncthreads();

  f32x4 acc[4][2] = {};
#pragma unroll
  for (int ks = 0; ks < 4; ++ks) {
    short8 af[4];
#pragma unroll
    for (int rf = 0; rf < 4; ++rf) {
      int row = rf * 16 + (lane & 15);
      int c16 = ks * 4 + (lane >> 4);
      int byteoff = row * 256 + ((c16 * 16) ^ ((row & 7) << 4));
      af[rf] = *(const short8*)((const char*)As + byteoff);
    }
    short8 wfr[2];
#pragma unroll
    for (int cf = 0; cf < 2; ++cf) {
      int n = colbase + cf * 16 + (lane & 15);
      int c16 = ks * 4 + (lane >> 4);
      int byteoff = n * 256 + ((c16 * 16) ^ ((n & 7) << 4));
      wfr[cf] = *(const short8*)((const char*)Ws + byteoff);
    }
#pragma unroll
    for (int rf = 0; rf < 4; ++rf)
#pragma unroll
      for (int cf = 0; cf < 2; ++cf)
        acc[rf][cf] = __builtin_amdgcn_mfma_f32_16x16x32_bf16(
            af[rf], wfr[cf], acc[rf][cf], 0, 0, 0);
  }

#pragma unroll
  for (int cf = 0; cf < 2; ++cf) {
    int c = colbase + cf * 16 + (lane & 15);
    float bbe = be[c];
#pragma unroll
    for (int rf = 0; rf < 4; ++rf)
#pragma unroll
      for (int j = 0; j < 4; ++j) {
        int lr = rf * 16 + (lane >> 4) * 4 + j;
        int r = row0 + lr;
        if (r < N_USER) {
          float v = acc[rf][cf][j] + bf2f(h0[(size_t)r * 128 + c]) +
                    degmask[lr] * bbe;
          v = (v >= 0.f) ? v : 0.01f * v;
          outp[(size_t)r * 128 + c] = f2bf(v);
        }
      }
  }
}

// ---------------------------------------------------------------------------
// Layer-2 fused double-GEMM (unchanged from R6), N=64, fp32 out:
//   out = A1@W[0:128] + A2@W[128:256] + b0 + (deg>0)*be
// ---------------------------------------------------------------------------
template <int N, bool LRELU, bool OUTBF16>
__global__ __launch_bounds__(256) void gemm2_k(
    const unsigned short* __restrict__ A1a, const unsigned short* __restrict__ A2a,
    const unsigned short* __restrict__ WTa, const float* __restrict__ b0a,
    const float* __restrict__ bea, const int* __restrict__ cura,
    void* __restrict__ outa,
    const unsigned short* __restrict__ A1b, const unsigned short* __restrict__ A2b,
    const unsigned short* __restrict__ WTb, const float* __restrict__ b0b,
    const float* __restrict__ beb, const int* __restrict__ curb,
    void* __restrict__ outb, int M, int nbA) {
  constexpr int BM = 64;
  constexpr int CPW = N / 4;
  constexpr int NCF = CPW / 16;
  __shared__ short As[BM * 128];
  __shared__ short Ws[N * 128];
  __shared__ float degmask[BM];

  int blk = blockIdx.x;
  const unsigned short* A1; const unsigned short* A2; const unsigned short* WT;
  const float* b0; const float* be; const int* cur; void* outv;
  if (blk < nbA) { A1 = A1a; A2 = A2a; WT = WTa; b0 = b0a; be = bea; cur = cura; outv = outa; }
  else { blk -= nbA; A1 = A1b; A2 = A2b; WT = WTb; b0 = b0b; be = beb; cur = curb; outv = outb; }

  const int tid = threadIdx.x;
  const int lane = tid & 63;
  const int wave = tid >> 6;
  const int row0 = blk * BM;
  const int colbase = wave * CPW;

  if (tid < BM) {
    int r = row0 + tid;
    degmask[tid] = (r < M && cur[r] > 0) ? 1.f : 0.f;
  }

  f32x4 acc[4][NCF] = {};

#pragma unroll
  for (int kh = 0; kh < 2; ++kh) {
    __syncthreads();
    const unsigned short* base = (kh == 0) ? A1 : A2;
#pragma unroll
    for (int it = 0; it < 4; ++it) {
      int chunk = tid + it * 256;
      int row = chunk >> 4, c16 = chunk & 15;
      int gr = row0 + row; if (gr > M - 1) gr = M - 1;
      short8 v = *(const short8*)(base + (size_t)gr * 128 + c16 * 8);
      int byteoff = row * 256 + ((c16 * 16) ^ ((row & 7) << 4));
      *(short8*)((char*)As + byteoff) = v;
    }
#pragma unroll
    for (int it = 0; it < (N * 16) / 256; ++it) {
      int chunk = tid + it * 256;
      int n = chunk >> 4, c16 = chunk & 15;
      short8 v = *(const short8*)(WT + (size_t)n * 256 + kh * 128 + c16 * 8);
      int byteoff = n * 256 + ((c16 * 16) ^ ((n & 7) << 4));
      *(short8*)((char*)Ws + byteoff) = v;
    }
    __syncthreads();

#pragma unroll
    for (int ks = 0; ks < 4; ++ks) {
      short8 af[4];
#pragma unroll
      for (int rf = 0; rf < 4; ++rf) {
        int row = rf * 16 + (lane & 15);
        int c16 = ks * 4 + (lane >> 4);
        int byteoff = row * 256 + ((c16 * 16) ^ ((row & 7) << 4));
        af[rf] = *(const short8*)((const char*)As + byteoff);
      }
      short8 wf[NCF];
#pragma unroll
      for (int cf = 0; cf < NCF; ++cf) {
        int n = colbase + cf * 16 + (lane & 15);
        int c16 = ks * 4 + (lane >> 4);
        int byteoff = n * 256 + ((c16 * 16) ^ ((n & 7) << 4));
        wf[cf] = *(const short8*)((const char*)Ws + byteoff);
      }
#pragma unroll
      for (int rf = 0; rf < 4; ++rf)
#pragma unroll
        for (int cf = 0; cf < NCF; ++cf)
          acc[rf][cf] = __builtin_amdgcn_mfma_f32_16x16x32_bf16(
              af[rf], wf[cf], acc[rf][cf], 0, 0, 0);
    }
  }

#pragma unroll
  for (int cf = 0; cf < NCF; ++cf) {
    int c = colbase + cf * 16 + (lane & 15);
    float bb0 = b0[c], bbe = be[c];
#pragma unroll
    for (int rf = 0; rf < 4; ++rf) {
#pragma unroll
      for (int j = 0; j < 4; ++j) {
        int lr = rf * 16 + (lane >> 4) * 4 + j;
        int r = row0 + lr;
        if (r < M) {
          float v = acc[rf][cf][j] + bb0 + degmask[lr] * bbe;
          if (LRELU) v = (v >= 0.f) ? v : 0.01f * v;
          if (OUTBF16)
            ((unsigned short*)outv)[(size_t)r * N + c] = f2bf(v);
          else
            ((float*)outv)[(size_t)r * N + c] = v;
        }
      }
    }
  }
}

extern "C" void kernel_launch(void* const* d_in, const int* in_sizes, int n_in,
                              void* d_out, int out_size, void* d_ws,
                              size_t ws_size, hipStream_t stream) {
  const float* emb_u = (const float*)d_in[0];
  const float* emb_i = (const float*)d_in[1];
  const float* W1_0  = (const float*)d_in[2];
  const float* b1_0  = (const float*)d_in[3];
  const float* W1_ui = (const float*)d_in[4];
  const float* b1_ui = (const float*)d_in[5];
  const float* W1_iu = (const float*)d_in[6];
  const float* b1_iu = (const float*)d_in[7];
  const float* W2_0  = (const float*)d_in[8];
  const float* b2_0  = (const float*)d_in[9];
  const float* W2_ui = (const float*)d_in[10];
  const float* b2_ui = (const float*)d_in[11];
  const float* W2_iu = (const float*)d_in[12];
  const float* b2_iu = (const float*)d_in[13];
  const int* src_ui = (const int*)d_in[14];
  const int* dst_ui = (const int*)d_in[15];
  const int* src_iu = (const int*)d_in[16];
  const int* dst_iu = (const int*)d_in[17];
  float* out = (float*)d_out;

  // ---- workspace layout (~129 MB) ----
  char* p = (char*)d_ws;
  unsigned short* WT1i = (unsigned short*)p; p += 65536;
  unsigned short* WT1u = (unsigned short*)p; p += 65536;
  unsigned short* WT2i = (unsigned short*)p; p += 32768;
  unsigned short* WT2u = (unsigned short*)p; p += 32768;
  int* cur_i = (int*)p; p += 400128;                 // degrees item-side
  int* cur_u = (int*)p; p += 400128;                 // degrees user-side
  int* csr_ui = (int*)p; p += (size_t)100032 * DEGCAP * 4;  // 12.8 MB
  int* csr_iu = (int*)p; p += (size_t)100032 * DEGCAP * 4;
  const size_t FB = (size_t)N_USER * 128 * 2;        // 25.6 MB
  unsigned short* ebu  = (unsigned short*)p; p += FB;  // emb bf16 -> later h_u
  unsigned short* ebi  = (unsigned short*)p; p += FB;  // emb bf16 -> later h_i
  unsigned short* aggA = (unsigned short*)p; p += FB;
  unsigned short* aggB = (unsigned short*)p; p += FB;
  // h0 scratch lives in d_out (dead until the final GEMM overwrites it)
  unsigned short* h0u = (unsigned short*)d_out;
  unsigned short* h0i = h0u + (size_t)N_USER * 128;

  hipMemsetAsync(cur_i, 0, 2 * 400128, stream);
  phase1_k<<<B_TOT, 256, 0, stream>>>(
      src_ui, dst_ui, cur_i, csr_ui, src_iu, dst_iu, cur_u, csr_iu,
      emb_u, emb_i, ebu, ebi,
      W1_0, W1_ui, W1_iu, W2_0, W2_ui, W2_iu,
      WT1i, WT1u, WT2i, WT2u, b1_0, h0u, h0i);

  // layer 1: gather-mean of emb (both dirs), then edge-GEMM + h0 + lrelu
  agg2_k<<<2 * 6250, 256, 0, stream>>>(
      ebu, cur_i, csr_ui, aggA, ebi, cur_u, csr_iu, aggB, 6250);
  egemm_k<<<2 * 1563, 256, 0, stream>>>(
      aggA, h0i, WT1i, b1_ui, cur_i, ebi,   // h_i -> ebi (eb dead after agg)
      aggB, h0u, WT1u, b1_iu, cur_u, ebu,   // h_u -> ebu
      1563);

  // layer 2: gather-mean of h (both dirs), fused double-GEMM -> fp32 d_out
  agg2_k<<<2 * 6250, 256, 0, stream>>>(
      ebu, cur_i, csr_ui, aggA, ebi, cur_u, csr_iu, aggB, 6250);
  gemm2_k<64, false, false><<<2 * 1563, 256, 0, stream>>>(
      ebi, aggA, WT2i, b2_0, b2_ui, cur_i, out + (size_t)N_USER * 64,
      ebu, aggB, WT2u, b2_0, b2_iu, cur_u, out, N_USER, 1563);
}

// Round 8
// 240.149 us; speedup vs baseline: 1.1649x; 1.1649x over previous
//
#include <hip/hip_runtime.h>

#define N_USER 100000
#define N_ITEM 100000
#define NEDGE  500000
#define DEGCAP 32

typedef __attribute__((ext_vector_type(8))) short short8;
typedef __attribute__((ext_vector_type(4))) float f32x4;

__device__ __forceinline__ unsigned short f2bf(float f) {
  union { float f; unsigned int u; } x{f};
  unsigned int r = x.u + 0x7fffu + ((x.u >> 16) & 1u);  // RTN-even
  return (unsigned short)(r >> 16);
}
__device__ __forceinline__ float bf2f(unsigned short u) {
  union { unsigned int u; float f; } x{(unsigned int)u << 16};
  return x.f;
}

// ---------------------------------------------------------------------------
// setup_k — sections (after block-index permutation):
//  [0,3908)      padded-CSR fill, both graphs (cur pre-zeroed by memset;
//                csr[d*32 + atomic-cursor] = src, nontemporal store)
//  [3908,16408)  emb fp32 -> bf16 conversion (both ntypes)
//  [16408,16792) transposed bf16 weight prep: WT[N][256]
// blockIdx is permuted by a modular bijection (b*7919 mod 16792) so the
// latency-bound fill blocks are interleaved with BW-bound conversion blocks
// from t=0 — the streaming hides the 1M-atomic latency (R6: fill ran first
// on an idle machine, setup_k = 105us at 2% VALU).
// ---------------------------------------------------------------------------
__global__ __launch_bounds__(256) void setup_k(
    const int* __restrict__ src_ui, const int* __restrict__ dst_ui,
    int* __restrict__ cur_i, int* __restrict__ csr_ui,
    const int* __restrict__ src_iu, const int* __restrict__ dst_iu,
    int* __restrict__ cur_u, int* __restrict__ csr_iu,
    const float* __restrict__ emb_u, const float* __restrict__ emb_i,
    unsigned short* __restrict__ ebu, unsigned short* __restrict__ ebi,
    const float* __restrict__ W10, const float* __restrict__ W1ui,
    const float* __restrict__ W1iu, const float* __restrict__ W20,
    const float* __restrict__ W2ui, const float* __restrict__ W2iu,
    unsigned short* __restrict__ WT1i, unsigned short* __restrict__ WT1u,
    unsigned short* __restrict__ WT2i, unsigned short* __restrict__ WT2u) {
  int b = (int)(((unsigned long long)blockIdx.x * 7919ull) % 16792ull);
  int tid = threadIdx.x;
  if (b < 3908) {
    const int *src, *dst; int *cur, *csr;
    int bb = b;
    if (bb < 1954) { src = src_ui; dst = dst_ui; cur = cur_i; csr = csr_ui; }
    else { bb -= 1954; src = src_iu; dst = dst_iu; cur = cur_u; csr = csr_iu; }
    int e = bb * 256 + tid;
    if (e < NEDGE) {
      int d = dst[e];
      int p = atomicAdd(&cur[d], 1);
      if (p < DEGCAP) __builtin_nontemporal_store(src[e], &csr[d * DEGCAP + p]);
    }
  } else if (b < 16408) {
    int blk = b - 3908;
    const float* src; unsigned short* dstp;
    if (blk < 6250) { src = emb_u; dstp = ebu; }
    else { blk -= 6250; src = emb_i; dstp = ebi; }
    size_t base = (size_t)blk * 2048 + (size_t)tid * 8;
    float4 x = *(const float4*)(src + base);
    float4 y = *(const float4*)(src + base + 4);
    short8 v{(short)f2bf(x.x), (short)f2bf(x.y), (short)f2bf(x.z), (short)f2bf(x.w),
             (short)f2bf(y.x), (short)f2bf(y.y), (short)f2bf(y.z), (short)f2bf(y.w)};
    *(short8*)(dstp + base) = v;
  } else {
    int t = (b - 16408) * 256 + tid;  // 0..98303
    if (t < 32768) {
      int n = t >> 8, k = t & 255;
      float v = (k < 128) ? W10[k * 128 + n] : W1ui[(k - 128) * 128 + n];
      WT1i[t] = f2bf(v);
    } else if (t < 65536) {
      int q = t - 32768; int n = q >> 8, k = q & 255;
      float v = (k < 128) ? W10[k * 128 + n] : W1iu[(k - 128) * 128 + n];
      WT1u[q] = f2bf(v);
    } else if (t < 81920) {
      int q = t - 65536; int n = q >> 8, k = q & 255;
      float v = (k < 128) ? W20[k * 64 + n] : W2ui[(k - 128) * 64 + n];
      WT2i[q] = f2bf(v);
    } else {
      int q = t - 81920; int n = q >> 8, k = q & 255;
      float v = (k < 128) ? W20[k * 64 + n] : W2iu[(k - 128) * 64 + n];
      WT2u[q] = f2bf(v);
    }
  }
}

// ---------------------------------------------------------------------------
// Gather-mean aggregation (bf16 src, 128-dim), both directions per dispatch.
// Padded CSR (stride 32, degree in cur). 16 lanes/node (short8/lane),
// 16 nodes/block, x4 unroll with next-group index prefetch. No LDS, high
// occupancy (R5 lesson: keep latency-bound gather out of LDS-capped kernels).
// ---------------------------------------------------------------------------
__global__ __launch_bounds__(256) void agg2_k(
    const unsigned short* __restrict__ featA, const int* __restrict__ curA,
    const int* __restrict__ csrA, unsigned short* __restrict__ outA,
    const unsigned short* __restrict__ featB, const int* __restrict__ curB,
    const int* __restrict__ csrB, unsigned short* __restrict__ outB,
    int nbA) {
  int b = blockIdx.x;
  const unsigned short* feat; const int* cur; const int* csr; unsigned short* out;
  if (b < nbA) { feat = featA; cur = curA; csr = csrA; out = outA; }
  else { b -= nbA; feat = featB; cur = curB; csr = csrB; out = outB; }
  int node = b * 16 + (threadIdx.x >> 4);
  int ln = threadIdx.x & 15;
  int deg = min(cur[node], DEGCAP);
  const int* cp = csr + (size_t)node * DEGCAP;
  float a[8] = {0, 0, 0, 0, 0, 0, 0, 0};
  int j = 0;
  if (j + 4 <= deg) {
    int i0 = cp[0], i1 = cp[1], i2 = cp[2], i3 = cp[3];
    for (;;) {
      bool more = (j + 8 <= deg);
      int n0, n1, n2, n3;
      if (more) { n0 = cp[j + 4]; n1 = cp[j + 5]; n2 = cp[j + 6]; n3 = cp[j + 7]; }
      short8 v0 = *(const short8*)(feat + (size_t)i0 * 128 + ln * 8);
      short8 v1 = *(const short8*)(feat + (size_t)i1 * 128 + ln * 8);
      short8 v2 = *(const short8*)(feat + (size_t)i2 * 128 + ln * 8);
      short8 v3 = *(const short8*)(feat + (size_t)i3 * 128 + ln * 8);
#pragma unroll
      for (int d = 0; d < 8; ++d)
        a[d] += (bf2f((unsigned short)v0[d]) + bf2f((unsigned short)v1[d])) +
                (bf2f((unsigned short)v2[d]) + bf2f((unsigned short)v3[d]));
      j += 4;
      if (!more) break;
      i0 = n0; i1 = n1; i2 = n2; i3 = n3;
    }
  }
  if (j + 2 <= deg) {
    int i0 = cp[j], i1 = cp[j + 1];
    short8 v0 = *(const short8*)(feat + (size_t)i0 * 128 + ln * 8);
    short8 v1 = *(const short8*)(feat + (size_t)i1 * 128 + ln * 8);
#pragma unroll
    for (int d = 0; d < 8; ++d)
      a[d] += bf2f((unsigned short)v0[d]) + bf2f((unsigned short)v1[d]);
    j += 2;
  }
  if (j < deg) {
    short8 v = *(const short8*)(feat + (size_t)cp[j] * 128 + ln * 8);
#pragma unroll
    for (int d = 0; d < 8; ++d) a[d] += bf2f((unsigned short)v[d]);
  }
  float sc = deg ? 1.f / (float)deg : 0.f;
  short8 pk;
#pragma unroll
  for (int d = 0; d < 8; ++d) pk[d] = (short)f2bf(a[d] * sc);
  *(short8*)(out + (size_t)node * 128 + ln * 8) = pk;
}

// ---------------------------------------------------------------------------
// Fused double-GEMM (bf16 MFMA, fp32 accum), both ntypes per dispatch:
//   out = A1@W[0:128] + A2@W[128:256] + b0 + (deg>0)*be  [, lrelu]
// A1, A2: [M][128] bf16. WT: [N][256] bf16 pre-transposed.
// BM=64, 4 waves, wave w owns cols [w*N/4,(w+1)*N/4). LDS XOR-swizzled.
// In-place out==A1 safe: block reads only its own rows, stage precedes write.
// Self-transform rides free on the K=256 fusion (R7 lesson: never
// materialize h0 through global).
// ---------------------------------------------------------------------------
template <int N, bool LRELU, bool OUTBF16>
__global__ __launch_bounds__(256) void gemm2_k(
    const unsigned short* __restrict__ A1a, const unsigned short* __restrict__ A2a,
    const unsigned short* __restrict__ WTa, const float* __restrict__ b0a,
    const float* __restrict__ bea, const int* __restrict__ cura,
    void* __restrict__ outa,
    const unsigned short* __restrict__ A1b, const unsigned short* __restrict__ A2b,
    const unsigned short* __restrict__ WTb, const float* __restrict__ b0b,
    const float* __restrict__ beb, const int* __restrict__ curb,
    void* __restrict__ outb, int M, int nbA) {
  constexpr int BM = 64;
  constexpr int CPW = N / 4;
  constexpr int NCF = CPW / 16;
  __shared__ short As[BM * 128];
  __shared__ short Ws[N * 128];
  __shared__ float degmask[BM];

  int blk = blockIdx.x;
  const unsigned short* A1; const unsigned short* A2; const unsigned short* WT;
  const float* b0; const float* be; const int* cur; void* outv;
  if (blk < nbA) { A1 = A1a; A2 = A2a; WT = WTa; b0 = b0a; be = bea; cur = cura; outv = outa; }
  else { blk -= nbA; A1 = A1b; A2 = A2b; WT = WTb; b0 = b0b; be = beb; cur = curb; outv = outb; }

  const int tid = threadIdx.x;
  const int lane = tid & 63;
  const int wave = tid >> 6;
  const int row0 = blk * BM;
  const int colbase = wave * CPW;

  if (tid < BM) {
    int r = row0 + tid;
    degmask[tid] = (r < M && cur[r] > 0) ? 1.f : 0.f;
  }

  f32x4 acc[4][NCF] = {};

#pragma unroll
  for (int kh = 0; kh < 2; ++kh) {
    __syncthreads();
    const unsigned short* base = (kh == 0) ? A1 : A2;
#pragma unroll
    for (int it = 0; it < 4; ++it) {
      int chunk = tid + it * 256;
      int row = chunk >> 4, c16 = chunk & 15;
      int gr = row0 + row; if (gr > M - 1) gr = M - 1;
      short8 v = *(const short8*)(base + (size_t)gr * 128 + c16 * 8);
      int byteoff = row * 256 + ((c16 * 16) ^ ((row & 7) << 4));
      *(short8*)((char*)As + byteoff) = v;
    }
#pragma unroll
    for (int it = 0; it < (N * 16) / 256; ++it) {
      int chunk = tid + it * 256;
      int n = chunk >> 4, c16 = chunk & 15;
      short8 v = *(const short8*)(WT + (size_t)n * 256 + kh * 128 + c16 * 8);
      int byteoff = n * 256 + ((c16 * 16) ^ ((n & 7) << 4));
      *(short8*)((char*)Ws + byteoff) = v;
    }
    __syncthreads();

#pragma unroll
    for (int ks = 0; ks < 4; ++ks) {
      short8 af[4];
#pragma unroll
      for (int rf = 0; rf < 4; ++rf) {
        int row = rf * 16 + (lane & 15);
        int c16 = ks * 4 + (lane >> 4);
        int byteoff = row * 256 + ((c16 * 16) ^ ((row & 7) << 4));
        af[rf] = *(const short8*)((const char*)As + byteoff);
      }
      short8 wf[NCF];
#pragma unroll
      for (int cf = 0; cf < NCF; ++cf) {
        int n = colbase + cf * 16 + (lane & 15);
        int c16 = ks * 4 + (lane >> 4);
        int byteoff = n * 256 + ((c16 * 16) ^ ((n & 7) << 4));
        wf[cf] = *(const short8*)((const char*)Ws + byteoff);
      }
#pragma unroll
      for (int rf = 0; rf < 4; ++rf)
#pragma unroll
        for (int cf = 0; cf < NCF; ++cf)
          acc[rf][cf] = __builtin_amdgcn_mfma_f32_16x16x32_bf16(
              af[rf], wf[cf], acc[rf][cf], 0, 0, 0);
    }
  }

  // C/D layout: col=lane&15, row=(lane>>4)*4+j  [m89 verified]
#pragma unroll
  for (int cf = 0; cf < NCF; ++cf) {
    int c = colbase + cf * 16 + (lane & 15);
    float bb0 = b0[c], bbe = be[c];
#pragma unroll
    for (int rf = 0; rf < 4; ++rf) {
#pragma unroll
      for (int j = 0; j < 4; ++j) {
        int lr = rf * 16 + (lane >> 4) * 4 + j;
        int r = row0 + lr;
        if (r < M) {
          float v = acc[rf][cf][j] + bb0 + degmask[lr] * bbe;
          if (LRELU) v = (v >= 0.f) ? v : 0.01f * v;
          if (OUTBF16)
            ((unsigned short*)outv)[(size_t)r * N + c] = f2bf(v);
          else
            ((float*)outv)[(size_t)r * N + c] = v;
        }
      }
    }
  }
}

extern "C" void kernel_launch(void* const* d_in, const int* in_sizes, int n_in,
                              void* d_out, int out_size, void* d_ws,
                              size_t ws_size, hipStream_t stream) {
  const float* emb_u = (const float*)d_in[0];
  const float* emb_i = (const float*)d_in[1];
  const float* W1_0  = (const float*)d_in[2];
  const float* b1_0  = (const float*)d_in[3];
  const float* W1_ui = (const float*)d_in[4];
  const float* b1_ui = (const float*)d_in[5];
  const float* W1_iu = (const float*)d_in[6];
  const float* b1_iu = (const float*)d_in[7];
  const float* W2_0  = (const float*)d_in[8];
  const float* b2_0  = (const float*)d_in[9];
  const float* W2_ui = (const float*)d_in[10];
  const float* b2_ui = (const float*)d_in[11];
  const float* W2_iu = (const float*)d_in[12];
  const float* b2_iu = (const float*)d_in[13];
  const int* src_ui = (const int*)d_in[14];
  const int* dst_ui = (const int*)d_in[15];
  const int* src_iu = (const int*)d_in[16];
  const int* dst_iu = (const int*)d_in[17];
  float* out = (float*)d_out;

  // ---- workspace layout (~130 MB) ----
  char* p = (char*)d_ws;
  unsigned short* WT1i = (unsigned short*)p; p += 65536;
  unsigned short* WT1u = (unsigned short*)p; p += 65536;
  unsigned short* WT2i = (unsigned short*)p; p += 32768;
  unsigned short* WT2u = (unsigned short*)p; p += 32768;
  int* cur_i = (int*)p; p += 400128;                 // degrees item-side
  int* cur_u = (int*)p; p += 400128;                 // degrees user-side
  int* csr_ui = (int*)p; p += (size_t)100032 * DEGCAP * 4;  // 12.8 MB
  int* csr_iu = (int*)p; p += (size_t)100032 * DEGCAP * 4;
  const size_t FB = (size_t)N_USER * 128 * 2;        // 25.6 MB
  unsigned short* ebu  = (unsigned short*)p; p += FB;  // -> hu (in place)
  unsigned short* ebi  = (unsigned short*)p; p += FB;  // -> hi (in place)
  unsigned short* aggA = (unsigned short*)p; p += FB;
  unsigned short* aggB = (unsigned short*)p; p += FB;
  unsigned short* hu = ebu;
  unsigned short* hi = ebi;

  const int GG = (N_USER + 63) / 64;  // 1563

  hipMemsetAsync(cur_i, 0, 2 * 400128, stream);
  setup_k<<<16792, 256, 0, stream>>>(src_ui, dst_ui, cur_i, csr_ui,
                                     src_iu, dst_iu, cur_u, csr_iu,
                                     emb_u, emb_i, ebu, ebi,
                                     W1_0, W1_ui, W1_iu, W2_0, W2_ui, W2_iu,
                                     WT1i, WT1u, WT2i, WT2u);

  // ---- layer 1: gather-mean (both dirs), fused double-GEMM + lrelu ----
  agg2_k<<<2 * 6250, 256, 0, stream>>>(
      ebu, cur_i, csr_ui, aggA, ebi, cur_u, csr_iu, aggB, 6250);
  gemm2_k<128, true, true><<<2 * GG, 256, 0, stream>>>(
      ebi, aggA, WT1i, b1_0, b1_ui, cur_i, hi,
      ebu, aggB, WT1u, b1_0, b1_iu, cur_u, hu, N_USER, GG);

  // ---- layer 2: gather-mean (both dirs), fused double-GEMM -> fp32 out ----
  agg2_k<<<2 * 6250, 256, 0, stream>>>(
      hu, cur_i, csr_ui, aggA, hi, cur_u, csr_iu, aggB, 6250);
  gemm2_k<64, false, false><<<2 * 1563, 256, 0, stream>>>(
      hi, aggA, WT2i, b2_0, b2_ui, cur_i, out + (size_t)N_USER * 64,
      hu, aggB, WT2u, b2_0, b2_iu, cur_u, out, N_USER, 1563);
}